// Round 4
// baseline (486.118 us; speedup 1.0000x reference)
//
#include <hip/hip_runtime.h>
#include <stdint.h>

#define DEV __device__ __forceinline__
typedef unsigned short u16;
typedef __attribute__((ext_vector_type(8))) short bf16x8;
typedef __attribute__((ext_vector_type(4))) float f32x4;

#define AS1 __attribute__((address_space(1)))
#define AS3 __attribute__((address_space(3)))
#define WAITVM0 asm volatile("s_waitcnt vmcnt(0)" ::: "memory")
// scores pre-scaled by 1/sqrt(64) * log2(e) inside the Q-projection epilogue
#define QSCALE 0.18033688011112042f

DEV u16 f2bf(float f) {
  union { float f; uint32_t u; } x; x.f = f;
  uint32_t r = x.u + 0x7fffu + ((x.u >> 16) & 1u);
  return (u16)(r >> 16);
}

DEV uint32_t cvt_pk_bf16(float a, float b) {
  uint32_t r;
  asm("v_cvt_pk_bf16_f32 %0, %1, %2" : "=v"(r) : "v"(a), "v"(b));
  return r;
}

// ---------------- f32 -> bf16 convert, two tensors in one launch ----------------
__global__ __launch_bounds__(256) void k_cvt2(const float* __restrict__ a, const float* __restrict__ bsrc,
                                              u16* __restrict__ oa, u16* __restrict__ ob, int n4) {
  int i = blockIdx.x * blockDim.x + threadIdx.x;
  const float* s;
  u16* o;
  int k;
  if (i < n4) { s = a; o = oa; k = i; }
  else        { s = bsrc; o = ob; k = i - n4; }
  float4 v = reinterpret_cast<const float4*>(s)[k];
  reinterpret_cast<ushort4*>(o)[k] = make_ushort4(f2bf(v.x), f2bf(v.y), f2bf(v.z), f2bf(v.w));
}

// ---------------- batched weight transpose+convert: W f32 [K][M] -> WT bf16 [M][K] ----------------
struct WTJob { const float* W; u16* WT; int K, M, msh, start; };
struct WTJobs { WTJob j[12]; };

__global__ void k_wT_all(WTJobs jobs) {
  __shared__ float tile[32][33];
  int b = blockIdx.x;
  int i = 0;
#pragma unroll
  for (int t = 1; t < 12; ++t)
    if (b >= jobs.j[t].start) i = t;
  const WTJob J = jobs.j[i];
  int rel = b - J.start;
  int m0 = (rel & ((1 << J.msh) - 1)) << 5;
  int k0 = (rel >> J.msh) << 5;
  int tx = threadIdx.x, ty = threadIdx.y;  // (32,8)
#pragma unroll
  for (int q = 0; q < 4; ++q)
    tile[ty + q * 8][tx] = J.W[(size_t)(k0 + ty + q * 8) * J.M + m0 + tx];
  __syncthreads();
#pragma unroll
  for (int q = 0; q < 4; ++q)
    J.WT[(size_t)(m0 + ty + q * 8) * J.K + k0 + tx] = f2bf(tile[tx][ty + q * 8]);
}

// ---- global->LDS staging of an R x 64 bf16 tile (128B rows), XOR-swizzled source ----
template<int R>
DEV void stage_tile(const u16* __restrict__ g, int strideElems, u16* lds, int tid, int wv) {
#pragma unroll
  for (int t = 0; t < R / 32; ++t) {
    int idx = t * 256 + tid;
    int row = idx >> 3;
    int b = (idx & 7) << 4;
    int sb = b ^ ((row & 7) << 4);
    const char* src = (const char*)g + (size_t)row * strideElems * 2 + sb;
    char* dst = (char*)lds + (size_t)(t * 256 + wv * 64) * 16;  // wave-uniform base; HW adds lane*16
    __builtin_amdgcn_global_load_lds((const AS1 void*)src, (AS3 void*)dst, 16, 0, 0);
  }
}

// swizzled b128 fragment read from a 64-col bf16 tile
DEV bf16x8 lds_frag(const u16* lds, int row, int kel) {
  int off = row * 128 + ((kel * 2) ^ ((row & 7) << 4));
  return *(const bf16x8*)((const char*)lds + off);
}

// ---------------- GEMM: C[n][m] = A[n][:] . WT[m][:] + bias[m] ----------------
// 128x128 tile, BK=64, 4 waves (2x2), double-buffered global_load_lds staging.
// MODE: 0=f32 out, 2=bf16 relu out
template<int MODE>
__global__ __launch_bounds__(256) void k_gemm(const u16* __restrict__ A, int lda,
                                              const u16* __restrict__ BT,
                                              const float* __restrict__ bias,
                                              void* __restrict__ C, int ldc, int K) {
  __shared__ __align__(16) u16 A_lds[2][128 * 64];
  __shared__ __align__(16) u16 B_lds[2][128 * 64];
  const int tid = threadIdx.x, lane = tid & 63, wv = tid >> 6;
  const int wm = wv >> 1, wn = wv & 1;
  const int bm0 = blockIdx.y * 128, bn0 = blockIdx.x * 128;
  const int lr = lane & 15, lk = (lane >> 4) * 8, r0 = (lane >> 4) * 4;

  f32x4 acc[4][4];
#pragma unroll
  for (int i = 0; i < 4; ++i)
#pragma unroll
    for (int j = 0; j < 4; ++j) acc[i][j] = f32x4{0.f, 0.f, 0.f, 0.f};

  stage_tile<128>(A + (size_t)bm0 * lda, lda, A_lds[0], tid, wv);
  stage_tile<128>(BT + (size_t)bn0 * K, K, B_lds[0], tid, wv);
  WAITVM0;
  __builtin_amdgcn_s_barrier();

  int cur = 0;
  for (int k0 = 0; k0 < K; k0 += 64) {
    if (k0 + 64 < K) {
      stage_tile<128>(A + (size_t)bm0 * lda + k0 + 64, lda, A_lds[cur ^ 1], tid, wv);
      stage_tile<128>(BT + (size_t)bn0 * K + k0 + 64, K, B_lds[cur ^ 1], tid, wv);
    }
#pragma unroll
    for (int kk = 0; kk < 2; ++kk) {
      bf16x8 af[4], bfr[4];
#pragma unroll
      for (int i = 0; i < 4; ++i) af[i] = lds_frag(A_lds[cur], wm * 64 + i * 16 + lr, kk * 32 + lk);
#pragma unroll
      for (int j = 0; j < 4; ++j) bfr[j] = lds_frag(B_lds[cur], wn * 64 + j * 16 + lr, kk * 32 + lk);
#pragma unroll
      for (int i = 0; i < 4; ++i)
#pragma unroll
        for (int j = 0; j < 4; ++j)
          acc[i][j] = __builtin_amdgcn_mfma_f32_16x16x32_bf16(af[i], bfr[j], acc[i][j], 0, 0, 0);
    }
    WAITVM0;
    __builtin_amdgcn_s_barrier();
    cur ^= 1;
  }

#pragma unroll
  for (int j = 0; j < 4; ++j) {
    int col = bn0 + wn * 64 + j * 16 + lr;
    float bv = bias[col];
#pragma unroll
    for (int i = 0; i < 4; ++i) {
      int rowb = bm0 + wm * 64 + i * 16 + r0;
      if constexpr (MODE == 0) {
#pragma unroll
        for (int r = 0; r < 4; ++r)
          ((float*)C)[(size_t)(rowb + r) * ldc + col] = acc[i][j][r] + bv;
      } else {
#pragma unroll
        for (int r = 0; r < 4; ++r) {
          float v = fmaxf(acc[i][j][r] + bv, 0.f);
          ((u16*)C)[(size_t)(rowb + r) * ldc + col] = f2bf(v);
        }
      }
    }
  }
}

// ---------------- fused QKV projection: N=3072 segments Q|K|V, 128x128 tile ----------------
// seg0 -> Qb bf16 scaled by QSCALE; seg1 -> Kb bf16; seg2 -> Vt transposed bf16.
__global__ __launch_bounds__(256) void k_qkv(const u16* __restrict__ Aq, const u16* __restrict__ Akv,
                                             const u16* __restrict__ BT,
                                             const float* __restrict__ bq, const float* __restrict__ bk,
                                             const float* __restrict__ bv,
                                             u16* __restrict__ Qb, u16* __restrict__ Kb,
                                             u16* __restrict__ Vt, int K) {
  __shared__ __align__(16) u16 A_lds[2][128 * 64];
  __shared__ __align__(16) u16 B_lds[2][128 * 64];
  const int tid = threadIdx.x, lane = tid & 63, wv = tid >> 6;
  const int wm = wv >> 1, wn = wv & 1;
  const int bm0 = blockIdx.y * 128, bn0 = blockIdx.x * 128;
  const int seg = bn0 >> 10;
  const u16* A = (seg == 0) ? Aq : Akv;
  const int lr = lane & 15, lk = (lane >> 4) * 8, r0 = (lane >> 4) * 4;

  f32x4 acc[4][4];
#pragma unroll
  for (int i = 0; i < 4; ++i)
#pragma unroll
    for (int j = 0; j < 4; ++j) acc[i][j] = f32x4{0.f, 0.f, 0.f, 0.f};

  stage_tile<128>(A + (size_t)bm0 * K, K, A_lds[0], tid, wv);
  stage_tile<128>(BT + (size_t)bn0 * K, K, B_lds[0], tid, wv);
  WAITVM0;
  __builtin_amdgcn_s_barrier();

  int cur = 0;
  for (int k0 = 0; k0 < K; k0 += 64) {
    if (k0 + 64 < K) {
      stage_tile<128>(A + (size_t)bm0 * K + k0 + 64, K, A_lds[cur ^ 1], tid, wv);
      stage_tile<128>(BT + (size_t)bn0 * K + k0 + 64, K, B_lds[cur ^ 1], tid, wv);
    }
#pragma unroll
    for (int kk = 0; kk < 2; ++kk) {
      bf16x8 af[4], bfr[4];
#pragma unroll
      for (int i = 0; i < 4; ++i) af[i] = lds_frag(A_lds[cur], wm * 64 + i * 16 + lr, kk * 32 + lk);
#pragma unroll
      for (int j = 0; j < 4; ++j) bfr[j] = lds_frag(B_lds[cur], wn * 64 + j * 16 + lr, kk * 32 + lk);
#pragma unroll
      for (int i = 0; i < 4; ++i)
#pragma unroll
        for (int j = 0; j < 4; ++j)
          acc[i][j] = __builtin_amdgcn_mfma_f32_16x16x32_bf16(af[i], bfr[j], acc[i][j], 0, 0, 0);
    }
    WAITVM0;
    __builtin_amdgcn_s_barrier();
    cur ^= 1;
  }

#pragma unroll
  for (int j = 0; j < 4; ++j) {
    int col = bn0 + wn * 64 + j * 16 + lr;
    int cl = col & 1023;
#pragma unroll
    for (int i = 0; i < 4; ++i) {
      int rowb = bm0 + wm * 64 + i * 16 + r0;
      if (seg == 0) {
        float bb = bq[cl];
#pragma unroll
        for (int r = 0; r < 4; ++r)
          Qb[(size_t)(rowb + r) * 1024 + cl] = f2bf((acc[i][j][r] + bb) * QSCALE);
      } else if (seg == 1) {
        float bb = bk[cl];
#pragma unroll
        for (int r = 0; r < 4; ++r)
          Kb[(size_t)(rowb + r) * 1024 + cl] = f2bf(acc[i][j][r] + bb);
      } else {
        float bb = bv[cl];
        int bidx = rowb >> 11, t = rowb & 2047;
        ushort4 o = make_ushort4(f2bf(acc[i][j][0] + bb), f2bf(acc[i][j][1] + bb),
                                 f2bf(acc[i][j][2] + bb), f2bf(acc[i][j][3] + bb));
        *reinterpret_cast<ushort4*>(&Vt[((size_t)bidx * 1024 + cl) * 2048 + t]) = o;
      }
    }
  }
}

// ---------------- fused residual LayerNorm (row=1024), dual f32/bf16 out ----------------
__global__ __launch_bounds__(256) void k_ln(const float* __restrict__ Rm, const float* __restrict__ X,
                                            const float* __restrict__ g, const float* __restrict__ be,
                                            float* __restrict__ Y, u16* __restrict__ Yb) {
  int row = blockIdx.x;
  size_t base4 = (size_t)row * 256;
  int t = threadIdx.x;
  float4 a = reinterpret_cast<const float4*>(Rm)[base4 + t];
  float4 x = reinterpret_cast<const float4*>(X)[base4 + t];
  float v0 = a.x + x.x, v1 = a.y + x.y, v2 = a.z + x.z, v3 = a.w + x.w;
  float s = v0 + v1 + v2 + v3;
  float ss = v0 * v0 + v1 * v1 + v2 * v2 + v3 * v3;
#pragma unroll
  for (int m = 1; m < 64; m <<= 1) { s += __shfl_xor(s, m); ss += __shfl_xor(ss, m); }
  __shared__ float red[8];
  int wv = t >> 6;
  if ((t & 63) == 0) { red[wv] = s; red[4 + wv] = ss; }
  __syncthreads();
  s = red[0] + red[1] + red[2] + red[3];
  ss = red[4] + red[5] + red[6] + red[7];
  float mean = s * (1.f / 1024.f);
  float var = ss * (1.f / 1024.f) - mean * mean;
  float rstd = rsqrtf(var + 1e-5f);
  float4 gv = reinterpret_cast<const float4*>(g)[t];
  float4 bv = reinterpret_cast<const float4*>(be)[t];
  float o0 = (v0 - mean) * rstd * gv.x + bv.x;
  float o1 = (v1 - mean) * rstd * gv.y + bv.y;
  float o2 = (v2 - mean) * rstd * gv.z + bv.z;
  float o3 = (v3 - mean) * rstd * gv.w + bv.w;
  reinterpret_cast<float4*>(Y)[base4 + t] = make_float4(o0, o1, o2, o3);
  if (Yb) {
    ushort4 ob = make_ushort4(f2bf(o0), f2bf(o1), f2bf(o2), f2bf(o3));
    reinterpret_cast<ushort4*>(Yb)[base4 + t] = ob;
  }
}

// ---------------- flash attention, swapped-operand in-register softmax ----------------
// QBLK=64 (4 waves x 16 q-rows), KVBLK=64, DH=64. Q pre-scaled by QSCALE -> exp2.
// All LDS fragment reads go through 2 precomputed swizzled byte offsets (fb0/fb1)
// + compile-time ds_read offset immediates; staging via 2 incrementing pointers.
template<bool CAUSAL>
__global__ __launch_bounds__(256) void k_attn(const u16* __restrict__ Q, const u16* __restrict__ Kg,
                                              const u16* __restrict__ Vt, u16* __restrict__ O, int T) {
  __shared__ __align__(16) u16 K_lds[2][64 * 64];
  __shared__ __align__(16) u16 V_lds[2][64 * 64];   // V^T tile: [dh][kv]
  __shared__ __align__(16) u16 p_lds[4][16 * 64];   // per-wave P rows, swizzled
  const int tid = threadIdx.x, lane = tid & 63, wv = tid >> 6;
  const int h = blockIdx.y, b = blockIdx.z;
  const int qx = CAUSAL ? (gridDim.x - 1 - blockIdx.x) : blockIdx.x;  // heavy tiles first
  const int q0 = qx * 64;
  const int qw = q0 + wv * 16;
  const int lq = lane & 15, g = lane >> 4;
  const int swz = (lq & 7) << 4;
  const int fb0 = lq * 128 + ((g * 16) ^ swz);        // kk=0 fragment byte offset
  const int fb1 = lq * 128 + ((g * 16 + 64) ^ swz);   // kk=1 fragment byte offset
  const size_t qkbase = ((size_t)b * T) * 1024 + h * 64;
  const size_t vbase = ((size_t)b * 1024 + h * 64) * T;

  bf16x8 aq0, aq1;
  {
    const u16* qp = Q + qkbase + (size_t)(qw + lq) * 1024 + g * 8;
    aq0 = *reinterpret_cast<const bf16x8*>(qp);
    aq1 = *reinterpret_cast<const bf16x8*>(qp + 32);
  }

  // staging: per-thread swizzled source, wave-uniform LDS dst (HW adds lane*16)
  const int srow = tid >> 3;
  const int ssb = ((tid & 7) << 4) ^ ((srow & 7) << 4);
  const char* ksrc = (const char*)(Kg + qkbase) + (size_t)srow * 2048 + ssb;
  const char* vsrc = (const char*)(Vt + vbase) + (size_t)srow * ((size_t)T * 2) + ssb;
  const int vstep2 = T * 64;  // 32 rows of V^T tile
  const uint32_t doff = (uint32_t)((tid & 192) << 4);  // wv*1024

  auto stage = [&](const char* kp, const char* vp, int buf) {
    char* kd = (char*)K_lds[buf] + doff;
    char* vd = (char*)V_lds[buf] + doff;
    __builtin_amdgcn_global_load_lds((const AS1 void*)kp, (AS3 void*)kd, 16, 0, 0);
    __builtin_amdgcn_global_load_lds((const AS1 void*)(kp + 65536), (AS3 void*)(kd + 4096), 16, 0, 0);
    __builtin_amdgcn_global_load_lds((const AS1 void*)vp, (AS3 void*)vd, 16, 0, 0);
    __builtin_amdgcn_global_load_lds((const AS1 void*)(vp + vstep2), (AS3 void*)(vd + 4096), 16, 0, 0);
  };

  f32x4 acc[4];
#pragma unroll
  for (int j = 0; j < 4; ++j) acc[j] = f32x4{0.f, 0.f, 0.f, 0.f};
  float lsum = 0.f;

  const int nt = CAUSAL ? (qx + 1) : (T >> 6);

  stage(ksrc, vsrc, 0);
  WAITVM0;
  __builtin_amdgcn_s_barrier();
  ksrc += 131072;  // 64 rows * 2048B
  vsrc += 128;     // 64 kv cols * 2B

  char* pw = (char*)p_lds[wv];
  int cur = 0;
  for (int it = 0; it < nt; ++it) {
    const int kv0 = it << 6;
    if (it + 1 < nt) {
      stage(ksrc, vsrc, cur ^ 1);
      ksrc += 131072;
      vsrc += 128;
    }
    const char* kb = (const char*)K_lds[cur];
    const char* vb = (const char*)V_lds[cur];
    // QK^T (swapped): st[j] holds S^T[kv-block j][q=lq]
    f32x4 st[4];
    __builtin_amdgcn_s_setprio(1);
#pragma unroll
    for (int j = 0; j < 4; ++j) {
      bf16x8 bk0 = *reinterpret_cast<const bf16x8*>(kb + fb0 + j * 2048);
      bf16x8 bk1 = *reinterpret_cast<const bf16x8*>(kb + fb1 + j * 2048);
      f32x4 t0 = f32x4{0.f, 0.f, 0.f, 0.f};
      t0 = __builtin_amdgcn_mfma_f32_16x16x32_bf16(bk0, aq0, t0, 0, 0, 0);
      t0 = __builtin_amdgcn_mfma_f32_16x16x32_bf16(bk1, aq1, t0, 0, 0, 0);
      st[j] = t0;
    }
    __builtin_amdgcn_s_setprio(0);
    // fixed-max softmax in log2 domain (scores pre-scaled)
    uint32_t pk[8];
    if (CAUSAL && it == nt - 1) {
      const int qrow = qw + lq;
#pragma unroll
      for (int j = 0; j < 4; ++j) {
        float p0 = __builtin_exp2f(st[j][0]);
        float p1 = __builtin_exp2f(st[j][1]);
        float p2 = __builtin_exp2f(st[j][2]);
        float p3 = __builtin_exp2f(st[j][3]);
        int kvb = kv0 + j * 16 + g * 4;
        p0 = (kvb > qrow) ? 0.f : p0;
        p1 = (kvb + 1 > qrow) ? 0.f : p1;
        p2 = (kvb + 2 > qrow) ? 0.f : p2;
        p3 = (kvb + 3 > qrow) ? 0.f : p3;
        lsum += (p0 + p1) + (p2 + p3);
        pk[2 * j] = cvt_pk_bf16(p0, p1);
        pk[2 * j + 1] = cvt_pk_bf16(p2, p3);
      }
    } else {
#pragma unroll
      for (int j = 0; j < 4; ++j) {
        float p0 = __builtin_exp2f(st[j][0]);
        float p1 = __builtin_exp2f(st[j][1]);
        float p2 = __builtin_exp2f(st[j][2]);
        float p3 = __builtin_exp2f(st[j][3]);
        lsum += (p0 + p1) + (p2 + p3);
        pk[2 * j] = cvt_pk_bf16(p0, p1);
        pk[2 * j + 1] = cvt_pk_bf16(p2, p3);
      }
    }
    // P -> per-wave LDS (swizzled b64 writes), read back as 2 b128 fragments
#pragma unroll
    for (int j = 0; j < 4; ++j)
      *reinterpret_cast<uint2*>(pw + lq * 128 + ((j * 32 + g * 8) ^ swz)) =
          make_uint2(pk[2 * j], pk[2 * j + 1]);
    bf16x8 pf0 = *reinterpret_cast<const bf16x8*>(pw + fb0);
    bf16x8 pf1 = *reinterpret_cast<const bf16x8*>(pw + fb1);
    // PV (swapped): acc[j2] = O^T[dh-block j2][q=lq]
    __builtin_amdgcn_s_setprio(1);
#pragma unroll
    for (int j2 = 0; j2 < 4; ++j2) {
      bf16x8 v0 = *reinterpret_cast<const bf16x8*>(vb + fb0 + j2 * 2048);
      bf16x8 v1 = *reinterpret_cast<const bf16x8*>(vb + fb1 + j2 * 2048);
      acc[j2] = __builtin_amdgcn_mfma_f32_16x16x32_bf16(v0, pf0, acc[j2], 0, 0, 0);
      acc[j2] = __builtin_amdgcn_mfma_f32_16x16x32_bf16(v1, pf1, acc[j2], 0, 0, 0);
    }
    __builtin_amdgcn_s_setprio(0);
    WAITVM0;
    __builtin_amdgcn_s_barrier();
    cur ^= 1;
  }

  lsum += __shfl_xor(lsum, 16);
  lsum += __shfl_xor(lsum, 32);
  float inv = 1.f / lsum;
  size_t rb = qkbase + (size_t)(qw + lq) * 1024;
#pragma unroll
  for (int j2 = 0; j2 < 4; ++j2) {
    ushort4 o = make_ushort4(f2bf(acc[j2][0] * inv), f2bf(acc[j2][1] * inv),
                             f2bf(acc[j2][2] * inv), f2bf(acc[j2][3] * inv));
    *reinterpret_cast<ushort4*>(&O[rb + j2 * 16 + g * 4]) = o;
  }
}

// ---------------- host orchestration ----------------
extern "C" void kernel_launch(void* const* d_in, const int* in_sizes, int n_in,
                              void* d_out, int out_size, void* d_ws, size_t ws_size,
                              hipStream_t stream) {
  const int T = 2048;
  const float* enc = (const float*)d_in[0];
  const float* outv = (const float*)d_in[1];
  auto F = [&](int i) { return (const float*)d_in[i]; };

  size_t off = 0;
  auto alloc = [&](size_t bytes) {
    void* p = (char*)d_ws + off;
    off += (bytes + 255) & ~(size_t)255;
    return p;
  };

  // transposed bf16 weights: q,k,v,o,W1,W2 per tag (q,k,v contiguous -> fused QKV BT)
  const int tdK[12] = {1024, 1024, 1024, 1024, 1024, 2048, 1024, 1024, 1024, 1024, 1024, 2048};
  const int tdM[12] = {1024, 1024, 1024, 1024, 2048, 1024, 1024, 1024, 1024, 1024, 2048, 1024};
  const int tdIdx[12] = {2, 4, 6, 8, 10, 12, 18, 20, 22, 24, 26, 28};
  u16* WT_[12];
  for (int i = 0; i < 12; ++i) WT_[i] = (u16*)alloc((size_t)tdK[i] * tdM[i] * 2);

  u16* Xb0 = (u16*)alloc(4096ull * 1024 * 2);
  u16* Eb = (u16*)alloc(4096ull * 1024 * 2);
  u16* Qb = (u16*)alloc(4096ull * 1024 * 2);
  u16* Kb = (u16*)alloc(4096ull * 1024 * 2);
  u16* Vt = (u16*)alloc(4096ull * 1024 * 2);
  u16* Ab = (u16*)alloc(4096ull * 1024 * 2);
  u16* Hb = (u16*)alloc(4096ull * 2048 * 2);
  u16* Xbc = (u16*)alloc(4096ull * 1024 * 2);
  float* Rf = (float*)alloc(4096ull * 1024 * 4);
  float* Xfa = (float*)alloc(4096ull * 1024 * 4);
  float* Xfb = (float*)alloc(4096ull * 1024 * 4);

  k_cvt2<<<8192, 256, 0, stream>>>(outv, enc, Xb0, Eb, 4096 * 1024 / 4);

  // one batched launch for all 12 weight transposes
  WTJobs jobs;
  int start = 0;
  for (int i = 0; i < 12; ++i) {
    int msh = (tdM[i] == 2048) ? 6 : 5;
    jobs.j[i] = {F(tdIdx[i]), WT_[i], tdK[i], tdM[i], msh, start};
    start += (tdM[i] >> 5) * (tdK[i] >> 5);
  }
  k_wT_all<<<start, dim3(32, 8), 0, stream>>>(jobs);

  dim3 gq(24, 32);    // fused QKV: N=3072, 128x128 tiles
  dim3 g1k(8, 32);    // N=1024
  dim3 g2k(16, 32);   // N=2048
  dim3 ga(32, 16, 2); // 32 q-tiles of 64 rows

  // ---- dd block ----
  k_qkv<<<gq, 256, 0, stream>>>(Xb0, Xb0, WT_[0], F(3), F(5), F(7), Qb, Kb, Vt, 1024);
  k_attn<true><<<ga, 256, 0, stream>>>(Qb, Kb, Vt, Ab, T);
  k_gemm<0><<<g1k, 256, 0, stream>>>(Ab, 1024, WT_[3], F(9), Rf, 1024, 1024);
  k_ln<<<4096, 256, 0, stream>>>(Rf, outv, F(14), F(15), Xfa, Xbc);
  k_gemm<2><<<g2k, 256, 0, stream>>>(Xbc, 1024, WT_[4], F(11), Hb, 2048, 1024);
  k_gemm<0><<<g1k, 256, 0, stream>>>(Hb, 2048, WT_[5], F(13), Rf, 1024, 2048);
  k_ln<<<4096, 256, 0, stream>>>(Rf, Xfa, F(16), F(17), Xfb, Xbc);

  // ---- ed block ----
  k_qkv<<<gq, 256, 0, stream>>>(Xbc, Eb, WT_[6], F(19), F(21), F(23), Qb, Kb, Vt, 1024);
  k_attn<false><<<ga, 256, 0, stream>>>(Qb, Kb, Vt, Ab, T);
  k_gemm<0><<<g1k, 256, 0, stream>>>(Ab, 1024, WT_[9], F(25), Rf, 1024, 1024);
  k_ln<<<4096, 256, 0, stream>>>(Rf, Xfb, F(30), F(31), Xfa, Xbc);
  k_gemm<2><<<g2k, 256, 0, stream>>>(Xbc, 1024, WT_[10], F(27), Hb, 2048, 1024);
  k_gemm<0><<<g1k, 256, 0, stream>>>(Hb, 2048, WT_[11], F(29), Rf, 1024, 2048);
  k_ln<<<4096, 256, 0, stream>>>(Rf, Xfa, F(32), F(33), (float*)d_out, (u16*)nullptr);
}

// Round 6
// 442.014 us; speedup vs baseline: 1.0998x; 1.0998x over previous
//
#include <hip/hip_runtime.h>
#include <stdint.h>

#define DEV __device__ __forceinline__
typedef unsigned short u16;
typedef __attribute__((ext_vector_type(8))) short bf16x8;
typedef __attribute__((ext_vector_type(4))) float f32x4;

#define AS1 __attribute__((address_space(1)))
#define AS3 __attribute__((address_space(3)))
#define WAITVM0 asm volatile("s_waitcnt vmcnt(0)" ::: "memory")
// scores pre-scaled by 1/sqrt(64) * log2(e) inside the Q-projection epilogue
#define QSCALE 0.18033688011112042f

DEV u16 f2bf(float f) {
  union { float f; uint32_t u; } x; x.f = f;
  uint32_t r = x.u + 0x7fffu + ((x.u >> 16) & 1u);
  return (u16)(r >> 16);
}

DEV uint32_t cvt_pk_bf16(float a, float b) {
  uint32_t r;
  asm("v_cvt_pk_bf16_f32 %0, %1, %2" : "=v"(r) : "v"(a), "v"(b));
  return r;
}

// ---------------- f32 -> bf16 convert, two tensors in one launch ----------------
__global__ __launch_bounds__(256) void k_cvt2(const float* __restrict__ a, const float* __restrict__ bsrc,
                                              u16* __restrict__ oa, u16* __restrict__ ob, int n4) {
  int i = blockIdx.x * blockDim.x + threadIdx.x;
  const float* s;
  u16* o;
  int k;
  if (i < n4) { s = a; o = oa; k = i; }
  else        { s = bsrc; o = ob; k = i - n4; }
  float4 v = reinterpret_cast<const float4*>(s)[k];
  reinterpret_cast<ushort4*>(o)[k] = make_ushort4(f2bf(v.x), f2bf(v.y), f2bf(v.z), f2bf(v.w));
}

// ---------------- batched weight transpose+convert: W f32 [K][M] -> WT bf16 [M][K] ----------------
struct WTJob { const float* W; u16* WT; int K, M, msh, start; };
struct WTJobs { WTJob j[12]; };

__global__ void k_wT_all(WTJobs jobs) {
  __shared__ float tile[32][33];
  int b = blockIdx.x;
  int i = 0;
#pragma unroll
  for (int t = 1; t < 12; ++t)
    if (b >= jobs.j[t].start) i = t;
  const WTJob J = jobs.j[i];
  int rel = b - J.start;
  int m0 = (rel & ((1 << J.msh) - 1)) << 5;
  int k0 = (rel >> J.msh) << 5;
  int tx = threadIdx.x, ty = threadIdx.y;  // (32,8)
#pragma unroll
  for (int q = 0; q < 4; ++q)
    tile[ty + q * 8][tx] = J.W[(size_t)(k0 + ty + q * 8) * J.M + m0 + tx];
  __syncthreads();
#pragma unroll
  for (int q = 0; q < 4; ++q)
    J.WT[(size_t)(m0 + ty + q * 8) * J.K + k0 + tx] = f2bf(tile[tx][ty + q * 8]);
}

// ---- global->LDS staging of an R x 64 bf16 tile (128B rows), XOR-swizzled source ----
template<int R>
DEV void stage_tile(const u16* __restrict__ g, int strideElems, u16* lds, int tid, int wv) {
#pragma unroll
  for (int t = 0; t < R / 32; ++t) {
    int idx = t * 256 + tid;
    int row = idx >> 3;
    int b = (idx & 7) << 4;
    int sb = b ^ ((row & 7) << 4);
    const char* src = (const char*)g + (size_t)row * strideElems * 2 + sb;
    char* dst = (char*)lds + (size_t)(t * 256 + wv * 64) * 16;  // wave-uniform base; HW adds lane*16
    __builtin_amdgcn_global_load_lds((const AS1 void*)src, (AS3 void*)dst, 16, 0, 0);
  }
}

// swizzled b128 fragment read from a 64-col bf16 tile
DEV bf16x8 lds_frag(const u16* lds, int row, int kel) {
  int off = row * 128 + ((kel * 2) ^ ((row & 7) << 4));
  return *(const bf16x8*)((const char*)lds + off);
}

// ---------------- GEMM: C[n][m] = A[n][:] . WT[m][:] + bias[m] ----------------
// 128x64 tile, BK=64, 4 waves. 3-stage pipeline with counted vmcnt (loads span
// 2 compute phases) + XCD-aware bijective block swizzle (nwg % 8 == 0 always).
// MODE: 0=f32 out, 2=bf16 relu out
template<int MODE>
__global__ __launch_bounds__(256) void k_gemm(const u16* __restrict__ A, int lda,
                                              const u16* __restrict__ BT,
                                              const float* __restrict__ bias,
                                              void* __restrict__ C, int ldc, int K) {
  __shared__ __align__(16) u16 A_lds[3][128 * 64];
  __shared__ __align__(16) u16 B_lds[3][64 * 64];
  const int tid = threadIdx.x, lane = tid & 63, wv = tid >> 6;
  const int wm = wv >> 1, wn = wv & 1;
  const int nwg = gridDim.x * gridDim.y;
  const int flat = blockIdx.y * gridDim.x + blockIdx.x;
  const int sw = (flat & 7) * (nwg >> 3) + (flat >> 3);
  const int bx = sw % gridDim.x, by = sw / gridDim.x;
  const int bm0 = by * 128, bn0 = bx * 64;
  const int lr = lane & 15, lk = (lane >> 4) * 8, r0 = (lane >> 4) * 4;

  f32x4 acc[4][2];
#pragma unroll
  for (int i = 0; i < 4; ++i)
#pragma unroll
    for (int j = 0; j < 2; ++j) acc[i][j] = f32x4{0.f, 0.f, 0.f, 0.f};

  auto stageT = [&](int s, int t) {
    stage_tile<128>(A + (size_t)bm0 * lda + t * 64, lda, A_lds[s], tid, wv);
    stage_tile<64>(BT + (size_t)bn0 * K + t * 64, K, B_lds[s], tid, wv);
  };

  const int nt = K >> 6;
  stageT(0, 0);
  stageT(1, 1);
  for (int t = 0; t < nt; ++t) {
    if (t + 2 < nt) {
      stageT((t + 2) % 3, t + 2);
      asm volatile("s_waitcnt vmcnt(12)" ::: "memory");   // {t+1,t+2} may stay in flight
    } else if (t + 1 < nt) {
      asm volatile("s_waitcnt vmcnt(6)" ::: "memory");    // {t+1} may stay in flight
    } else {
      asm volatile("s_waitcnt vmcnt(0)" ::: "memory");
    }
    __builtin_amdgcn_s_barrier();                          // tile t fully staged (all waves)
    const int cur = t % 3;
#pragma unroll
    for (int kk = 0; kk < 2; ++kk) {
      bf16x8 af[4], bfr[2];
#pragma unroll
      for (int i = 0; i < 4; ++i) af[i] = lds_frag(A_lds[cur], wm * 64 + i * 16 + lr, kk * 32 + lk);
#pragma unroll
      for (int j = 0; j < 2; ++j) bfr[j] = lds_frag(B_lds[cur], wn * 32 + j * 16 + lr, kk * 32 + lk);
#pragma unroll
      for (int i = 0; i < 4; ++i)
#pragma unroll
        for (int j = 0; j < 2; ++j)
          acc[i][j] = __builtin_amdgcn_mfma_f32_16x16x32_bf16(af[i], bfr[j], acc[i][j], 0, 0, 0);
    }
    __builtin_amdgcn_s_barrier();                          // all waves done reading tile t
  }

#pragma unroll
  for (int j = 0; j < 2; ++j) {
    int col = bn0 + wn * 32 + j * 16 + lr;
    float bv = bias[col];
#pragma unroll
    for (int i = 0; i < 4; ++i) {
      int rowb = bm0 + wm * 64 + i * 16 + r0;
      if constexpr (MODE == 0) {
#pragma unroll
        for (int r = 0; r < 4; ++r)
          ((float*)C)[(size_t)(rowb + r) * ldc + col] = acc[i][j][r] + bv;
      } else {
#pragma unroll
        for (int r = 0; r < 4; ++r) {
          float v = fmaxf(acc[i][j][r] + bv, 0.f);
          ((u16*)C)[(size_t)(rowb + r) * ldc + col] = f2bf(v);
        }
      }
    }
  }
}

// ---------------- fused QKV projection: N=3072 segments Q|K|V (128x64 tiles, 3-stage) ----------------
__global__ __launch_bounds__(256) void k_qkv(const u16* __restrict__ Aq, const u16* __restrict__ Akv,
                                             const u16* __restrict__ BT,
                                             const float* __restrict__ bq, const float* __restrict__ bk,
                                             const float* __restrict__ bv,
                                             u16* __restrict__ Qb, u16* __restrict__ Kb,
                                             u16* __restrict__ Vt, int K) {
  __shared__ __align__(16) u16 A_lds[3][128 * 64];
  __shared__ __align__(16) u16 B_lds[3][64 * 64];
  const int tid = threadIdx.x, lane = tid & 63, wv = tid >> 6;
  const int wm = wv >> 1, wn = wv & 1;
  const int nwg = gridDim.x * gridDim.y;
  const int flat = blockIdx.y * gridDim.x + blockIdx.x;
  const int sw = (flat & 7) * (nwg >> 3) + (flat >> 3);
  const int bx = sw % gridDim.x, by = sw / gridDim.x;
  const int bm0 = by * 128, bn0 = bx * 64;
  const int seg = bn0 >> 10;
  const u16* A = (seg == 0) ? Aq : Akv;
  const int lr = lane & 15, lk = (lane >> 4) * 8, r0 = (lane >> 4) * 4;

  f32x4 acc[4][2];
#pragma unroll
  for (int i = 0; i < 4; ++i)
#pragma unroll
    for (int j = 0; j < 2; ++j) acc[i][j] = f32x4{0.f, 0.f, 0.f, 0.f};

  auto stageT = [&](int s, int t) {
    stage_tile<128>(A + (size_t)bm0 * K + t * 64, K, A_lds[s], tid, wv);
    stage_tile<64>(BT + (size_t)bn0 * K + t * 64, K, B_lds[s], tid, wv);
  };

  const int nt = K >> 6;
  stageT(0, 0);
  stageT(1, 1);
  for (int t = 0; t < nt; ++t) {
    if (t + 2 < nt) {
      stageT((t + 2) % 3, t + 2);
      asm volatile("s_waitcnt vmcnt(12)" ::: "memory");
    } else if (t + 1 < nt) {
      asm volatile("s_waitcnt vmcnt(6)" ::: "memory");
    } else {
      asm volatile("s_waitcnt vmcnt(0)" ::: "memory");
    }
    __builtin_amdgcn_s_barrier();
    const int cur = t % 3;
#pragma unroll
    for (int kk = 0; kk < 2; ++kk) {
      bf16x8 af[4], bfr[2];
#pragma unroll
      for (int i = 0; i < 4; ++i) af[i] = lds_frag(A_lds[cur], wm * 64 + i * 16 + lr, kk * 32 + lk);
#pragma unroll
      for (int j = 0; j < 2; ++j) bfr[j] = lds_frag(B_lds[cur], wn * 32 + j * 16 + lr, kk * 32 + lk);
#pragma unroll
      for (int i = 0; i < 4; ++i)
#pragma unroll
        for (int j = 0; j < 2; ++j)
          acc[i][j] = __builtin_amdgcn_mfma_f32_16x16x32_bf16(af[i], bfr[j], acc[i][j], 0, 0, 0);
    }
    __builtin_amdgcn_s_barrier();
  }

#pragma unroll
  for (int j = 0; j < 2; ++j) {
    int col = bn0 + wn * 32 + j * 16 + lr;
    int cl = col & 1023;
#pragma unroll
    for (int i = 0; i < 4; ++i) {
      int rowb = bm0 + wm * 64 + i * 16 + r0;
      if (seg == 0) {
        float bb = bq[cl];
#pragma unroll
        for (int r = 0; r < 4; ++r)
          Qb[(size_t)(rowb + r) * 1024 + cl] = f2bf((acc[i][j][r] + bb) * QSCALE);
      } else if (seg == 1) {
        float bb = bk[cl];
#pragma unroll
        for (int r = 0; r < 4; ++r)
          Kb[(size_t)(rowb + r) * 1024 + cl] = f2bf(acc[i][j][r] + bb);
      } else {
        float bb = bv[cl];
        int bidx = rowb >> 11, t = rowb & 2047;
        ushort4 o = make_ushort4(f2bf(acc[i][j][0] + bb), f2bf(acc[i][j][1] + bb),
                                 f2bf(acc[i][j][2] + bb), f2bf(acc[i][j][3] + bb));
        *reinterpret_cast<ushort4*>(&Vt[((size_t)bidx * 1024 + cl) * 2048 + t]) = o;
      }
    }
  }
}

// ---------------- fused residual LayerNorm (row=1024), dual f32/bf16 out ----------------
__global__ __launch_bounds__(256) void k_ln(const float* __restrict__ Rm, const float* __restrict__ X,
                                            const float* __restrict__ g, const float* __restrict__ be,
                                            float* __restrict__ Y, u16* __restrict__ Yb) {
  int row = blockIdx.x;
  size_t base4 = (size_t)row * 256;
  int t = threadIdx.x;
  float4 a = reinterpret_cast<const float4*>(Rm)[base4 + t];
  float4 x = reinterpret_cast<const float4*>(X)[base4 + t];
  float v0 = a.x + x.x, v1 = a.y + x.y, v2 = a.z + x.z, v3 = a.w + x.w;
  float s = v0 + v1 + v2 + v3;
  float ss = v0 * v0 + v1 * v1 + v2 * v2 + v3 * v3;
#pragma unroll
  for (int m = 1; m < 64; m <<= 1) { s += __shfl_xor(s, m); ss += __shfl_xor(ss, m); }
  __shared__ float red[8];
  int wv = t >> 6;
  if ((t & 63) == 0) { red[wv] = s; red[4 + wv] = ss; }
  __syncthreads();
  s = red[0] + red[1] + red[2] + red[3];
  ss = red[4] + red[5] + red[6] + red[7];
  float mean = s * (1.f / 1024.f);
  float var = ss * (1.f / 1024.f) - mean * mean;
  float rstd = rsqrtf(var + 1e-5f);
  float4 gv = reinterpret_cast<const float4*>(g)[t];
  float4 bv = reinterpret_cast<const float4*>(be)[t];
  float o0 = (v0 - mean) * rstd * gv.x + bv.x;
  float o1 = (v1 - mean) * rstd * gv.y + bv.y;
  float o2 = (v2 - mean) * rstd * gv.z + bv.z;
  float o3 = (v3 - mean) * rstd * gv.w + bv.w;
  reinterpret_cast<float4*>(Y)[base4 + t] = make_float4(o0, o1, o2, o3);
  if (Yb) {
    ushort4 ob = make_ushort4(f2bf(o0), f2bf(o1), f2bf(o2), f2bf(o3));
    reinterpret_cast<ushort4*>(Yb)[base4 + t] = ob;
  }
}

// ---------------- flash attention, swapped softmax + p_lds P-exchange + causal pairing ----------------
// QBLK=64 (4 waves x 16 q-rows), KVBLK=64, DH=64. Q pre-scaled by QSCALE -> exp2.
// Causal: block x processes q-tiles (31-x, x) in ONE kv loop -> uniform 33 compute-steps/block.
template<bool CAUSAL>
__global__ __launch_bounds__(256) void k_attn(const u16* __restrict__ Q, const u16* __restrict__ Kg,
                                              const u16* __restrict__ Vt, u16* __restrict__ O, int T) {
  __shared__ __align__(16) u16 K_lds[2][64 * 64];
  __shared__ __align__(16) u16 V_lds[2][64 * 64];   // V^T tile: [dh][kv]
  __shared__ __align__(16) u16 p_lds[4][16 * 64];   // per-wave P rows, swizzled
  const int tid = threadIdx.x, lane = tid & 63, wv = tid >> 6;
  const int h = blockIdx.y, b = blockIdx.z;
  const int lq = lane & 15, g = lane >> 4;
  const int swz = (lq & 7) << 4;
  const int fb0 = lq * 128 + ((g * 16) ^ swz);
  const int fb1 = lq * 128 + ((g * 16 + 64) ^ swz);
  const size_t qkbase = ((size_t)b * T) * 1024 + h * 64;
  const size_t vbase = ((size_t)b * 1024 + h * 64) * T;

  const int qp = CAUSAL ? (31 - blockIdx.x) : blockIdx.x;  // primary q-tile
  const int qa = CAUSAL ? blockIdx.x : 0;                  // secondary (causal only)
  const int nt = CAUSAL ? (qp + 1) : (T >> 6);
  const int qwP = qp * 64 + wv * 16, qwA = qa * 64 + wv * 16;

  bf16x8 aqP0, aqP1, aqA0, aqA1;
  {
    const u16* qp_ = Q + qkbase + (size_t)(qwP + lq) * 1024 + g * 8;
    aqP0 = *reinterpret_cast<const bf16x8*>(qp_);
    aqP1 = *reinterpret_cast<const bf16x8*>(qp_ + 32);
    if constexpr (CAUSAL) {
      const u16* qa_ = Q + qkbase + (size_t)(qwA + lq) * 1024 + g * 8;
      aqA0 = *reinterpret_cast<const bf16x8*>(qa_);
      aqA1 = *reinterpret_cast<const bf16x8*>(qa_ + 32);
    }
  }

  // staging: per-thread swizzled source, wave-uniform LDS dst (HW adds lane*16)
  const int srow = tid >> 3;
  const int ssb = ((tid & 7) << 4) ^ ((srow & 7) << 4);
  const char* ksrc = (const char*)(Kg + qkbase) + (size_t)srow * 2048 + ssb;
  const char* vsrc = (const char*)(Vt + vbase) + (size_t)srow * ((size_t)T * 2) + ssb;
  const int vstep2 = T * 64;
  const uint32_t doff = (uint32_t)((tid & 192) << 4);

  auto stage = [&](const char* kp, const char* vp, int buf) {
    char* kd = (char*)K_lds[buf] + doff;
    char* vd = (char*)V_lds[buf] + doff;
    __builtin_amdgcn_global_load_lds((const AS1 void*)kp, (AS3 void*)kd, 16, 0, 0);
    __builtin_amdgcn_global_load_lds((const AS1 void*)(kp + 65536), (AS3 void*)(kd + 4096), 16, 0, 0);
    __builtin_amdgcn_global_load_lds((const AS1 void*)vp, (AS3 void*)vd, 16, 0, 0);
    __builtin_amdgcn_global_load_lds((const AS1 void*)(vp + vstep2), (AS3 void*)(vd + 4096), 16, 0, 0);
  };

  f32x4 accP[4], accA[4];
  float lsumP = 0.f, lsumA = 0.f;
#pragma unroll
  for (int j = 0; j < 4; ++j) { accP[j] = f32x4{0.f, 0.f, 0.f, 0.f}; accA[j] = f32x4{0.f, 0.f, 0.f, 0.f}; }

  char* pw = (char*)p_lds[wv];

  // one q-tile step against the staged KV tile
  auto qstep = [&](bf16x8 a0, bf16x8 a1, int qrow, bool domask, int kv0,
                   f32x4* acc, float& lsum, const char* kb, const char* vb) {
    f32x4 st[4];
    __builtin_amdgcn_s_setprio(1);
#pragma unroll
    for (int j = 0; j < 4; ++j) {
      bf16x8 bk0 = *reinterpret_cast<const bf16x8*>(kb + fb0 + j * 2048);
      bf16x8 bk1 = *reinterpret_cast<const bf16x8*>(kb + fb1 + j * 2048);
      f32x4 t0 = f32x4{0.f, 0.f, 0.f, 0.f};
      t0 = __builtin_amdgcn_mfma_f32_16x16x32_bf16(bk0, a0, t0, 0, 0, 0);
      t0 = __builtin_amdgcn_mfma_f32_16x16x32_bf16(bk1, a1, t0, 0, 0, 0);
      st[j] = t0;
    }
    __builtin_amdgcn_s_setprio(0);
    uint32_t pk[8];
    if (domask) {
#pragma unroll
      for (int j = 0; j < 4; ++j) {
        float p0 = __builtin_exp2f(st[j][0]);
        float p1 = __builtin_exp2f(st[j][1]);
        float p2 = __builtin_exp2f(st[j][2]);
        float p3 = __builtin_exp2f(st[j][3]);
        int kvb = kv0 + j * 16 + g * 4;
        p0 = (kvb > qrow) ? 0.f : p0;
        p1 = (kvb + 1 > qrow) ? 0.f : p1;
        p2 = (kvb + 2 > qrow) ? 0.f : p2;
        p3 = (kvb + 3 > qrow) ? 0.f : p3;
        lsum += (p0 + p1) + (p2 + p3);
        pk[2 * j] = cvt_pk_bf16(p0, p1);
        pk[2 * j + 1] = cvt_pk_bf16(p2, p3);
      }
    } else {
#pragma unroll
      for (int j = 0; j < 4; ++j) {
        float p0 = __builtin_exp2f(st[j][0]);
        float p1 = __builtin_exp2f(st[j][1]);
        float p2 = __builtin_exp2f(st[j][2]);
        float p3 = __builtin_exp2f(st[j][3]);
        lsum += (p0 + p1) + (p2 + p3);
        pk[2 * j] = cvt_pk_bf16(p0, p1);
        pk[2 * j + 1] = cvt_pk_bf16(p2, p3);
      }
    }
    // P -> per-wave LDS (swizzled b64 writes), read back as 2 b128 fragments
#pragma unroll
    for (int j = 0; j < 4; ++j)
      *reinterpret_cast<uint2*>(pw + lq * 128 + ((j * 32 + g * 8) ^ swz)) =
          make_uint2(pk[2 * j], pk[2 * j + 1]);
    bf16x8 pf0 = *reinterpret_cast<const bf16x8*>(pw + fb0);
    bf16x8 pf1 = *reinterpret_cast<const bf16x8*>(pw + fb1);
    // PV (swapped): acc[j2] = O^T[dh-block j2][q=lq]
    __builtin_amdgcn_s_setprio(1);
#pragma unroll
    for (int j2 = 0; j2 < 4; ++j2) {
      bf16x8 v0 = *reinterpret_cast<const bf16x8*>(vb + fb0 + j2 * 2048);
      bf16x8 v1 = *reinterpret_cast<const bf16x8*>(vb + fb1 + j2 * 2048);
      acc[j2] = __builtin_amdgcn_mfma_f32_16x16x32_bf16(v0, pf0, acc[j2], 0, 0, 0);
      acc[j2] = __builtin_amdgcn_mfma_f32_16x16x32_bf16(v1, pf1, acc[j2], 0, 0, 0);
    }
    __builtin_amdgcn_s_setprio(0);
  };

  stage(ksrc, vsrc, 0);
  WAITVM0;
  __builtin_amdgcn_s_barrier();
  ksrc += 131072;
  vsrc += 128;

  int cur = 0;
  for (int it = 0; it < nt; ++it) {
    const int kv0 = it << 6;
    if (it + 1 < nt) {
      stage(ksrc, vsrc, cur ^ 1);
      ksrc += 131072;
      vsrc += 128;
    }
    const char* kb = (const char*)K_lds[cur];
    const char* vb = (const char*)V_lds[cur];
    qstep(aqP0, aqP1, qwP + lq, CAUSAL && it == qp, kv0, accP, lsumP, kb, vb);
    if constexpr (CAUSAL) {
      if (it <= qa)
        qstep(aqA0, aqA1, qwA + lq, it == qa, kv0, accA, lsumA, kb, vb);
    }
    WAITVM0;
    __builtin_amdgcn_s_barrier();
    cur ^= 1;
  }

  lsumP += __shfl_xor(lsumP, 16);
  lsumP += __shfl_xor(lsumP, 32);
  float invP = 1.f / lsumP;
  size_t rbP = qkbase + (size_t)(qwP + lq) * 1024;
#pragma unroll
  for (int j2 = 0; j2 < 4; ++j2) {
    ushort4 o = make_ushort4(f2bf(accP[j2][0] * invP), f2bf(accP[j2][1] * invP),
                             f2bf(accP[j2][2] * invP), f2bf(accP[j2][3] * invP));
    *reinterpret_cast<ushort4*>(&O[rbP + j2 * 16 + g * 4]) = o;
  }
  if constexpr (CAUSAL) {
    lsumA += __shfl_xor(lsumA, 16);
    lsumA += __shfl_xor(lsumA, 32);
    float invA = 1.f / lsumA;
    size_t rbA = qkbase + (size_t)(qwA + lq) * 1024;
#pragma unroll
    for (int j2 = 0; j2 < 4; ++j2) {
      ushort4 o = make_ushort4(f2bf(accA[j2][0] * invA), f2bf(accA[j2][1] * invA),
                               f2bf(accA[j2][2] * invA), f2bf(accA[j2][3] * invA));
      *reinterpret_cast<ushort4*>(&O[rbA + j2 * 16 + g * 4]) = o;
    }
  }
}

// ---------------- host orchestration ----------------
extern "C" void kernel_launch(void* const* d_in, const int* in_sizes, int n_in,
                              void* d_out, int out_size, void* d_ws, size_t ws_size,
                              hipStream_t stream) {
  const int T = 2048;
  const float* enc = (const float*)d_in[0];
  const float* outv = (const float*)d_in[1];
  auto F = [&](int i) { return (const float*)d_in[i]; };

  size_t off = 0;
  auto alloc = [&](size_t bytes) {
    void* p = (char*)d_ws + off;
    off += (bytes + 255) & ~(size_t)255;
    return p;
  };

  // transposed bf16 weights: q,k,v,o,W1,W2 per tag (q,k,v contiguous -> fused QKV BT)
  const int tdK[12] = {1024, 1024, 1024, 1024, 1024, 2048, 1024, 1024, 1024, 1024, 1024, 2048};
  const int tdM[12] = {1024, 1024, 1024, 1024, 2048, 1024, 1024, 1024, 1024, 1024, 2048, 1024};
  const int tdIdx[12] = {2, 4, 6, 8, 10, 12, 18, 20, 22, 24, 26, 28};
  u16* WT_[12];
  for (int i = 0; i < 12; ++i) WT_[i] = (u16*)alloc((size_t)tdK[i] * tdM[i] * 2);

  u16* Xb0 = (u16*)alloc(4096ull * 1024 * 2);
  u16* Eb = (u16*)alloc(4096ull * 1024 * 2);
  u16* Qb = (u16*)alloc(4096ull * 1024 * 2);
  u16* Kb = (u16*)alloc(4096ull * 1024 * 2);
  u16* Vt = (u16*)alloc(4096ull * 1024 * 2);
  u16* Ab = (u16*)alloc(4096ull * 1024 * 2);
  u16* Hb = (u16*)alloc(4096ull * 2048 * 2);
  u16* Xbc = (u16*)alloc(4096ull * 1024 * 2);
  float* Rf = (float*)alloc(4096ull * 1024 * 4);
  float* Xfa = (float*)alloc(4096ull * 1024 * 4);
  float* Xfb = (float*)alloc(4096ull * 1024 * 4);

  k_cvt2<<<8192, 256, 0, stream>>>(outv, enc, Xb0, Eb, 4096 * 1024 / 4);

  WTJobs jobs;
  int start = 0;
  for (int i = 0; i < 12; ++i) {
    int msh = (tdM[i] == 2048) ? 6 : 5;
    jobs.j[i] = {F(tdIdx[i]), WT_[i], tdK[i], tdM[i], msh, start};
    start += (tdM[i] >> 5) * (tdK[i] >> 5);
  }
  k_wT_all<<<start, dim3(32, 8), 0, stream>>>(jobs);

  dim3 gq(48, 32);     // fused QKV: N=3072, 128x64 tiles
  dim3 g1k(16, 32);    // N=1024
  dim3 g2k(32, 32);    // N=2048 (FFN1), BN=64
  dim3 gac(16, 16, 2); // causal: 16 paired q-tile blocks
  dim3 gan(32, 16, 2); // noncausal: 32 q-tile blocks

  // ---- dd block ----
  k_qkv<<<gq, 256, 0, stream>>>(Xb0, Xb0, WT_[0], F(3), F(5), F(7), Qb, Kb, Vt, 1024);
  k_attn<true><<<gac, 256, 0, stream>>>(Qb, Kb, Vt, Ab, T);
  k_gemm<0><<<g1k, 256, 0, stream>>>(Ab, 1024, WT_[3], F(9), Rf, 1024, 1024);
  k_ln<<<4096, 256, 0, stream>>>(Rf, outv, F(14), F(15), Xfa, Xbc);
  k_gemm<2><<<g2k, 256, 0, stream>>>(Xbc, 1024, WT_[4], F(11), Hb, 2048, 1024);
  k_gemm<0><<<g1k, 256, 0, stream>>>(Hb, 2048, WT_[5], F(13), Rf, 1024, 2048);
  k_ln<<<4096, 256, 0, stream>>>(Rf, Xfa, F(16), F(17), Xfb, Xbc);

  // ---- ed block ----
  k_qkv<<<gq, 256, 0, stream>>>(Xbc, Eb, WT_[6], F(19), F(21), F(23), Qb, Kb, Vt, 1024);
  k_attn<false><<<gan, 256, 0, stream>>>(Qb, Kb, Vt, Ab, T);
  k_gemm<0><<<g1k, 256, 0, stream>>>(Ab, 1024, WT_[9], F(25), Rf, 1024, 1024);
  k_ln<<<4096, 256, 0, stream>>>(Rf, Xfb, F(30), F(31), Xfa, Xbc);
  k_gemm<2><<<g2k, 256, 0, stream>>>(Xbc, 1024, WT_[10], F(27), Hb, 2048, 1024);
  k_gemm<0><<<g1k, 256, 0, stream>>>(Hb, 2048, WT_[11], F(29), Rf, 1024, 2048);
  k_ln<<<4096, 256, 0, stream>>>(Rf, Xfa, F(32), F(33), (float*)d_out, (u16*)nullptr);
}